// Round 1
// baseline (5645.756 us; speedup 1.0000x reference)
//
#include <hip/hip_runtime.h>

#define SEQ 2048
#define BATCH 4
#define DMODEL 1024
#define NHEAD 16
#define HEAD_DIM 64

// ---------------- GEMM: C[M,N] = A[M,K] @ B[K,N] + bias[N] ----------------
// BM=BN=64, BK=16, 256 threads, each thread computes a 4x4 micro-tile.
template<int BM, int BN, int BK>
__global__ __launch_bounds__(256) void gemm_bias_f32(
    const float* __restrict__ A, const float* __restrict__ B,
    const float* __restrict__ bias, float* __restrict__ C,
    int M, int N, int K)
{
    __shared__ float As[BK][BM + 4];   // A tile stored transposed [k][m], padded
    __shared__ float Bs[BK][BN + 4];   // B tile [k][n], padded

    const int tid = threadIdx.x;
    const int tx = tid & 15;           // 0..15 -> col group
    const int ty = tid >> 4;           // 0..15 -> row group
    const int rowBase = blockIdx.y * BM;
    const int colBase = blockIdx.x * BN;

    float acc[4][4];
    #pragma unroll
    for (int i = 0; i < 4; ++i)
        #pragma unroll
        for (int j = 0; j < 4; ++j) acc[i][j] = 0.f;

    for (int k0 = 0; k0 < K; k0 += BK) {
        // load A tile 64x16 (float4 per thread), store transposed
        {
            int r  = tid >> 2;             // 0..63
            int kc = (tid & 3) << 2;       // 0,4,8,12
            float4 av = *reinterpret_cast<const float4*>(
                &A[(size_t)(rowBase + r) * K + k0 + kc]);
            As[kc + 0][r] = av.x;
            As[kc + 1][r] = av.y;
            As[kc + 2][r] = av.z;
            As[kc + 3][r] = av.w;
        }
        // load B tile 16x64 (float4 per thread)
        {
            int kr = tid >> 4;             // 0..15
            int c  = (tid & 15) << 2;      // 0..60
            float4 bv = *reinterpret_cast<const float4*>(
                &B[(size_t)(k0 + kr) * N + colBase + c]);
            *reinterpret_cast<float4*>(&Bs[kr][c]) = bv;
        }
        __syncthreads();

        #pragma unroll
        for (int kk = 0; kk < BK; ++kk) {
            float4 av = *reinterpret_cast<const float4*>(&As[kk][ty << 2]);
            float4 bv = *reinterpret_cast<const float4*>(&Bs[kk][tx << 2]);
            float a[4] = {av.x, av.y, av.z, av.w};
            float b[4] = {bv.x, bv.y, bv.z, bv.w};
            #pragma unroll
            for (int i = 0; i < 4; ++i)
                #pragma unroll
                for (int j = 0; j < 4; ++j)
                    acc[i][j] += a[i] * b[j];
        }
        __syncthreads();
    }

    #pragma unroll
    for (int i = 0; i < 4; ++i) {
        int row = rowBase + (ty << 2) + i;
        #pragma unroll
        for (int j = 0; j < 4; ++j) {
            int col = colBase + (tx << 2) + j;
            C[(size_t)row * N + col] = acc[i][j] + bias[col];
        }
    }
}

// ---------------- Flash-style attention, f32 ----------------
// qkv layout: [B, S, 3, H, Dh] flat = [B, S, 3072]
// block = (b, h, 16 q-rows); 256 threads = 4 waves, 4 q-rows per wave.
// K/V chunks of 64 keys staged in LDS (padded stride 65).
__global__ __launch_bounds__(256) void attn_f32(
    const float* __restrict__ qkv,
    float* __restrict__ attn_out)       // [B, S, 1024]
{
    __shared__ float Ks[64 * 65];
    __shared__ float Vs[64 * 65];
    __shared__ float Qs[16 * 64];
    __shared__ float Ps[16 * 64];

    const int tid  = threadIdx.x;
    const int lane = tid & 63;
    const int wave = tid >> 6;          // 0..3

    const int qt = blockIdx.x & 127;    // q tile (16 rows each)
    const int bh = blockIdx.x >> 7;     // 0..63
    const int b  = bh >> 4;
    const int h  = bh & 15;

    const size_t base = (size_t)b * SEQ * 3072;

    // load Q tile (16 rows x 64 dims)
    {
        int r = tid >> 4;               // 0..15
        int c = (tid & 15) << 2;        // 0..60
        float4 qv = *reinterpret_cast<const float4*>(
            &qkv[base + (size_t)(qt * 16 + r) * 3072 + h * 64 + c]);
        *reinterpret_cast<float4*>(&Qs[r * 64 + c]) = qv;
    }

    float m[4], l[4], O[4];
    #pragma unroll
    for (int r = 0; r < 4; ++r) { m[r] = -1e30f; l[r] = 0.f; O[r] = 0.f; }
    const int qrow0 = wave << 2;

    for (int c = 0; c < SEQ / 64; ++c) {
        __syncthreads();
        // cooperative load of K,V chunk (64 keys x 64 dims each)
        #pragma unroll
        for (int i = 0; i < 16; ++i) {
            int e = i * 256 + tid;
            int j = e >> 6, d = e & 63;
            size_t g = base + (size_t)(c * 64 + j) * 3072 + h * 64 + d;
            Ks[j * 65 + d] = qkv[g + 1024];
            Vs[j * 65 + d] = qkv[g + 2048];
        }
        __syncthreads();

        // score phase: lane = key index within chunk
        float s[4] = {0.f, 0.f, 0.f, 0.f};
        for (int d = 0; d < 64; d += 4) {
            float k0 = Ks[lane * 65 + d + 0];
            float k1 = Ks[lane * 65 + d + 1];
            float k2 = Ks[lane * 65 + d + 2];
            float k3 = Ks[lane * 65 + d + 3];
            #pragma unroll
            for (int r = 0; r < 4; ++r) {
                float4 qv = *reinterpret_cast<const float4*>(&Qs[(qrow0 + r) * 64 + d]);
                s[r] += qv.x * k0 + qv.y * k1 + qv.z * k2 + qv.w * k3;
            }
        }
        float alpha[4];
        #pragma unroll
        for (int r = 0; r < 4; ++r) {
            float sv = s[r] * 0.125f;   // HEAD_DIM^-0.5
            float cm = sv;
            #pragma unroll
            for (int off = 32; off > 0; off >>= 1)
                cm = fmaxf(cm, __shfl_xor(cm, off, 64));
            float mnew = fmaxf(m[r], cm);
            float p = __expf(sv - mnew);
            float cs = p;
            #pragma unroll
            for (int off = 32; off > 0; off >>= 1)
                cs += __shfl_xor(cs, off, 64);
            alpha[r] = __expf(m[r] - mnew);
            l[r] = l[r] * alpha[r] + cs;
            m[r] = mnew;
            Ps[(qrow0 + r) * 64 + lane] = p;
        }

        // PV phase: lane = head dim
        #pragma unroll
        for (int r = 0; r < 4; ++r) O[r] *= alpha[r];
        for (int j = 0; j < 64; ++j) {
            float vv = Vs[j * 65 + lane];
            #pragma unroll
            for (int r = 0; r < 4; ++r)
                O[r] += Ps[(qrow0 + r) * 64 + j] * vv;
        }
    }

    #pragma unroll
    for (int r = 0; r < 4; ++r) {
        int srow = qt * 16 + qrow0 + r;
        attn_out[((size_t)b * SEQ + srow) * DMODEL + h * 64 + lane] = O[r] / l[r];
    }
}

extern "C" void kernel_launch(void* const* d_in, const int* in_sizes, int n_in,
                              void* d_out, int out_size, void* d_ws, size_t ws_size,
                              hipStream_t stream) {
    (void)in_sizes; (void)n_in; (void)out_size; (void)ws_size;
    const float* x     = (const float*)d_in[0];
    const float* W_qkv = (const float*)d_in[1];
    const float* b_qkv = (const float*)d_in[2];
    const float* W_out = (const float*)d_in[3];
    const float* b_out = (const float*)d_in[4];
    float* out = (float*)d_out;

    float* qkv  = (float*)d_ws;                       // 8192*3072 f32 = 96 MB
    float* attn = qkv + (size_t)8192 * 3072;          // 8192*1024 f32 = 32 MB

    const int M = BATCH * SEQ;                        // 8192

    dim3 blk(256);
    // qkv = x @ W_qkv + b_qkv
    gemm_bias_f32<64, 64, 16><<<dim3(3 * DMODEL / 64, M / 64), blk, 0, stream>>>(
        x, W_qkv, b_qkv, qkv, M, 3 * DMODEL, DMODEL);
    // attention
    attn_f32<<<dim3(BATCH * NHEAD * (SEQ / 16)), blk, 0, stream>>>(qkv, attn);
    // out = attn @ W_out + b_out
    gemm_bias_f32<64, 64, 16><<<dim3(DMODEL / 64, M / 64), blk, 0, stream>>>(
        attn, W_out, b_out, out, M, DMODEL, DMODEL);
}

// Round 2
// 338.245 us; speedup vs baseline: 16.6913x; 16.6913x over previous
//
#include <hip/hip_runtime.h>
#include <hip/hip_bf16.h>

#define SEQ 2048
#define BATCH 4
#define DMODEL 1024
#define NHEAD 16

typedef __attribute__((ext_vector_type(8))) __bf16 bf16x8;
typedef __attribute__((ext_vector_type(4))) __bf16 bf16x4;
typedef __attribute__((ext_vector_type(4))) float f32x4;

// async global->LDS, 16B per lane. LDS dest must be wave-uniform base; HW adds lane*16.
__device__ __forceinline__ void gload_lds16(const void* g, void* l) {
    __builtin_amdgcn_global_load_lds(
        (const __attribute__((address_space(1))) void*)g,
        (__attribute__((address_space(3))) void*)l, 16, 0, 0);
}

// ---------------- cast f32 -> bf16 (vectorized) ----------------
__global__ __launch_bounds__(256) void cast_f32_to_bf16(
    const float* __restrict__ in, __bf16* __restrict__ out, int n4)
{
    int i = blockIdx.x * 256 + threadIdx.x;
    if (i >= n4) return;
    float4 v = reinterpret_cast<const float4*>(in)[i];
    bf16x4 o = { (__bf16)v.x, (__bf16)v.y, (__bf16)v.z, (__bf16)v.w };
    reinterpret_cast<bf16x4*>(out)[i] = o;
}

// ---------------- W [K][N] f32 -> WT [N][K] bf16 ----------------
__global__ __launch_bounds__(256) void trans_w(
    const float* __restrict__ W, __bf16* __restrict__ WT, int K, int N)
{
    __shared__ float t[32][33];
    const int tid = threadIdx.x;
    const int n0 = blockIdx.x * 32, k0 = blockIdx.y * 32;
    const int tx = tid & 31, ty = tid >> 5;     // ty 0..7
    #pragma unroll
    for (int j = 0; j < 4; ++j)
        t[ty + 8*j][tx] = W[(size_t)(k0 + ty + 8*j) * N + n0 + tx];
    __syncthreads();
    #pragma unroll
    for (int j = 0; j < 4; ++j)
        WT[(size_t)(n0 + ty + 8*j) * K + k0 + tx] = (__bf16)t[tx][ty + 8*j];
}

// ---------------- V slice of qkv -> Vt [B*H][64][SEQ] ----------------
__global__ __launch_bounds__(256) void prep_vt(
    const __bf16* __restrict__ qkv, __bf16* __restrict__ Vt)
{
    __shared__ __bf16 t[64][72];
    const int tid = threadIdx.x;
    const int sc = blockIdx.x & 31, bh = blockIdx.x >> 5;
    const int b = bh >> 4, h = bh & 15;
    const size_t base = ((size_t)b * SEQ + sc * 64) * 3072 + 2 * DMODEL + h * 64;
    #pragma unroll
    for (int i = 0; i < 2; ++i) {
        int s = i * 32 + (tid >> 3), d0 = (tid & 7) * 8;
        bf16x8 v = *(const bf16x8*)&qkv[base + (size_t)s * 3072 + d0];
        #pragma unroll
        for (int j = 0; j < 8; ++j) t[s][d0 + j] = v[j];
    }
    __syncthreads();
    #pragma unroll
    for (int i = 0; i < 2; ++i) {
        int d = i * 32 + (tid >> 3), s0 = (tid & 7) * 8;
        bf16x8 v;
        #pragma unroll
        for (int j = 0; j < 8; ++j) v[j] = t[s0 + j][d];
        *(bf16x8*)&Vt[((size_t)bh * 64 + d) * SEQ + sc * 64 + s0] = v;
    }
}

// ---------------- m97-style bf16 MFMA GEMM: C = A[M,K] @ BT[N,K]^T + bias ----------------
// 128x128 tile, BK=32, 256 threads (4 waves 2x2), 16x16x32 MFMA, global_load_lds staging.
template<int F32OUT>
__global__ __launch_bounds__(256) void gemm_bf16_mfma(
    const __bf16* __restrict__ A, const __bf16* __restrict__ BT,
    const float* __restrict__ bias, void* __restrict__ Cout,
    int M, int N, int K)
{
    __shared__ __attribute__((aligned(128))) char As[8192];   // [128][32] bf16
    __shared__ __attribute__((aligned(128))) char Bs[8192];   // [128][32] bf16

    const int tid = threadIdx.x, wv = tid >> 6, ln = tid & 63;
    const int rowBase = blockIdx.y * 128;
    const int colBase = blockIdx.x * 128;
    const int mq = (wv >> 1) * 64, nq = (wv & 1) * 64;
    const int lg = ln >> 4, lc = ln & 15;
    const int srow = ln >> 2;            // staging: row within 16-row chunk
    const int skoff = (ln & 3) * 8;      // staging: k elem offset

    f32x4 acc[4][4] = {};

    for (int k0 = 0; k0 < K; k0 += 32) {
        __syncthreads();
        #pragma unroll
        for (int i = 0; i < 2; ++i) {
            int ch = wv * 2 + i;         // 0..7, wave-uniform
            gload_lds16(A  + (size_t)(rowBase + ch*16 + srow) * K + k0 + skoff, As + ch*1024);
            gload_lds16(BT + (size_t)(colBase + ch*16 + srow) * K + k0 + skoff, Bs + ch*1024);
        }
        __syncthreads();

        bf16x8 af[4], bf[4];
        #pragma unroll
        for (int m = 0; m < 4; ++m)
            af[m] = *(const bf16x8*)(As + (mq + m*16 + lc) * 64 + lg * 16);
        #pragma unroll
        for (int n = 0; n < 4; ++n)
            bf[n] = *(const bf16x8*)(Bs + (nq + n*16 + lc) * 64 + lg * 16);
        #pragma unroll
        for (int m = 0; m < 4; ++m)
            #pragma unroll
            for (int n = 0; n < 4; ++n)
                acc[m][n] = __builtin_amdgcn_mfma_f32_16x16x32_bf16(af[m], bf[n], acc[m][n], 0, 0, 0);
    }

    #pragma unroll
    for (int m = 0; m < 4; ++m) {
        int row0 = rowBase + mq + m * 16 + lg * 4;
        #pragma unroll
        for (int n = 0; n < 4; ++n) {
            int col = colBase + nq + n * 16 + lc;
            float bv = bias[col];
            #pragma unroll
            for (int r = 0; r < 4; ++r) {
                float v = acc[m][n][r] + bv;
                if (F32OUT) ((float*)Cout)[(size_t)(row0 + r) * N + col] = v;
                else        ((__bf16*)Cout)[(size_t)(row0 + r) * N + col] = (__bf16)v;
            }
        }
    }
}

// ---------------- MFMA flash attention ----------------
// block: 256 threads = 4 waves; each wave owns 32 q-rows; block = 128 q-rows of one (b,h).
// KV chunk = 64 keys. K,V staged via global_load_lds with pre-swizzled source;
// fragment ds_read_b128 are bank-conflict-free (XOR swizzle byte^((row&7)<<4)).
__global__ __launch_bounds__(256) void attn_mfma(
    const __bf16* __restrict__ qkv,   // [B][S][3072]
    const __bf16* __restrict__ Vt,    // [B*H][64][SEQ]
    __bf16* __restrict__ attn_out)    // [B*S][DMODEL]
{
    __shared__ __attribute__((aligned(128))) char Ks[8192];      // [64 key][64 d] swizzled
    __shared__ __attribute__((aligned(128))) char Vs[8192];      // [64 d][64 key] swizzled
    __shared__ __attribute__((aligned(128))) char Ps[4][4096];   // per-wave [32 q][64 key] swizzled

    const int tid = threadIdx.x, wv = tid >> 6, ln = tid & 63;
    const int qt = blockIdx.x & 15;
    const int bh = blockIdx.x >> 4;
    const int b = bh >> 4, h = bh & 15;
    const int lg = ln >> 4, lc = ln & 15;

    const size_t qkvbase = (size_t)b * SEQ * 3072;

    // Q fragments in registers (scaled scores handled in softmax)
    bf16x8 qf[2][2];
    #pragma unroll
    for (int m = 0; m < 2; ++m) {
        int qrow = qt * 128 + wv * 32 + m * 16 + lc;
        #pragma unroll
        for (int t = 0; t < 2; ++t)
            qf[m][t] = *(const bf16x8*)&qkv[qkvbase + (size_t)qrow * 3072 + h * 64 + t * 32 + lg * 8];
    }

    f32x4 Oacc[2][4] = {};
    float mrun[2][4], lrun[2][4];
    #pragma unroll
    for (int m = 0; m < 2; ++m)
        #pragma unroll
        for (int r = 0; r < 4; ++r) { mrun[m][r] = -1e30f; lrun[m][r] = 0.f; }

    const int strow = ln >> 3;      // staging row within 8-row chunk
    const int stslot = ln & 7;

    char* PsW = Ps[wv];

    for (int c = 0; c < SEQ / 64; ++c) {
        __syncthreads();
        #pragma unroll
        for (int i = 0; i < 2; ++i) {
            int ch = wv * 2 + i;                 // wave-uniform chunk id 0..7
            int row = ch * 8 + strow;            // 0..63
            int slot = stslot ^ (row & 7);       // pre-swizzled source slot
            gload_lds16(&qkv[qkvbase + (size_t)(c * 64 + row) * 3072 + DMODEL + h * 64 + slot * 8],
                        Ks + ch * 1024);
            gload_lds16(&Vt[((size_t)bh * 64 + row) * SEQ + c * 64 + slot * 8],
                        Vs + ch * 1024);
        }
        __syncthreads();

        // ---- S = Q K^T ----
        f32x4 Sacc[2][4] = {};
        #pragma unroll
        for (int n = 0; n < 4; ++n) {
            int row = n * 16 + lc;
            int xo = (row & 7) << 4;
            #pragma unroll
            for (int t = 0; t < 2; ++t) {
                bf16x8 kf = *(const bf16x8*)(Ks + row * 128 + ((t * 64 + lg * 16) ^ xo));
                #pragma unroll
                for (int m = 0; m < 2; ++m)
                    Sacc[m][n] = __builtin_amdgcn_mfma_f32_16x16x32_bf16(qf[m][t], kf, Sacc[m][n], 0, 0, 0);
            }
        }

        // ---- online softmax (f32), write P (bf16) to per-wave LDS ----
        #pragma unroll
        for (int m = 0; m < 2; ++m) {
            #pragma unroll
            for (int r = 0; r < 4; ++r) {
                float v0 = Sacc[m][0][r] * 0.125f;
                float v1 = Sacc[m][1][r] * 0.125f;
                float v2 = Sacc[m][2][r] * 0.125f;
                float v3 = Sacc[m][3][r] * 0.125f;
                float mx = fmaxf(fmaxf(v0, v1), fmaxf(v2, v3));
                mx = fmaxf(mx, __shfl_xor(mx, 1));
                mx = fmaxf(mx, __shfl_xor(mx, 2));
                mx = fmaxf(mx, __shfl_xor(mx, 4));
                mx = fmaxf(mx, __shfl_xor(mx, 8));
                float mold = mrun[m][r];
                float mnew = fmaxf(mold, mx);
                float al = __expf(mold - mnew);
                mrun[m][r] = mnew;
                float p0 = __expf(v0 - mnew);
                float p1 = __expf(v1 - mnew);
                float p2 = __expf(v2 - mnew);
                float p3 = __expf(v3 - mnew);
                float ls = p0 + p1 + p2 + p3;
                ls += __shfl_xor(ls, 1);
                ls += __shfl_xor(ls, 2);
                ls += __shfl_xor(ls, 4);
                ls += __shfl_xor(ls, 8);
                lrun[m][r] = lrun[m][r] * al + ls;
                int prow = m * 16 + lg * 4 + r;
                char* pb = PsW + prow * 128;
                int xo = (prow & 7) << 4;
                int c0 = lc * 2;
                *(__bf16*)(pb + ((c0      ) ^ xo)) = (__bf16)p0;
                *(__bf16*)(pb + ((c0 + 32) ^ xo)) = (__bf16)p1;
                *(__bf16*)(pb + ((c0 + 64) ^ xo)) = (__bf16)p2;
                *(__bf16*)(pb + ((c0 + 96) ^ xo)) = (__bf16)p3;
                #pragma unroll
                for (int n = 0; n < 4; ++n) Oacc[m][n][r] *= al;
            }
        }

        // ---- O += P V  (P per-wave: no barrier needed) ----
        #pragma unroll
        for (int t = 0; t < 2; ++t) {
            bf16x8 pf[2], vf[4];
            #pragma unroll
            for (int m = 0; m < 2; ++m) {
                int row = m * 16 + lc;
                pf[m] = *(const bf16x8*)(PsW + row * 128 + ((t * 64 + lg * 16) ^ ((row & 7) << 4)));
            }
            #pragma unroll
            for (int n = 0; n < 4; ++n) {
                int row = n * 16 + lc;
                vf[n] = *(const bf16x8*)(Vs + row * 128 + ((t * 64 + lg * 16) ^ ((row & 7) << 4)));
                #pragma unroll
                for (int m = 0; m < 2; ++m)
                    Oacc[m][n] = __builtin_amdgcn_mfma_f32_16x16x32_bf16(pf[m], vf[n], Oacc[m][n], 0, 0, 0);
            }
        }
    }

    // ---- epilogue: normalize and store bf16 ----
    #pragma unroll
    for (int m = 0; m < 2; ++m) {
        #pragma unroll
        for (int r = 0; r < 4; ++r) {
            float inv = 1.0f / lrun[m][r];
            int row = qt * 128 + wv * 32 + m * 16 + lg * 4 + r;
            #pragma unroll
            for (int n = 0; n < 4; ++n)
                attn_out[((size_t)b * SEQ + row) * DMODEL + h * 64 + n * 16 + lc] =
                    (__bf16)(Oacc[m][n][r] * inv);
        }
    }
}

extern "C" void kernel_launch(void* const* d_in, const int* in_sizes, int n_in,
                              void* d_out, int out_size, void* d_ws, size_t ws_size,
                              hipStream_t stream) {
    (void)in_sizes; (void)n_in; (void)out_size; (void)ws_size;
    const float* x     = (const float*)d_in[0];
    const float* W_qkv = (const float*)d_in[1];
    const float* b_qkv = (const float*)d_in[2];
    const float* W_out = (const float*)d_in[3];
    const float* b_out = (const float*)d_in[4];
    float* out = (float*)d_out;

    char* ws = (char*)d_ws;
    __bf16* xb    = (__bf16*)(ws);                          // 16 MB
    __bf16* WqkvT = (__bf16*)(ws + ((size_t)16 << 20));     // 6 MB
    __bf16* WoutT = (__bf16*)(ws + ((size_t)22 << 20));     // 2 MB
    __bf16* qkvb  = (__bf16*)(ws + ((size_t)24 << 20));     // 48 MB
    __bf16* Vt    = (__bf16*)(ws + ((size_t)72 << 20));     // 16 MB
    __bf16* attnb = (__bf16*)(ws + ((size_t)88 << 20));     // 16 MB

    const int M = BATCH * SEQ;  // 8192

    cast_f32_to_bf16<<<dim3(M * DMODEL / 4 / 256), 256, 0, stream>>>(x, xb, M * DMODEL / 4);
    trans_w<<<dim3(3 * DMODEL / 32, DMODEL / 32), 256, 0, stream>>>(W_qkv, WqkvT, DMODEL, 3 * DMODEL);
    trans_w<<<dim3(DMODEL / 32, DMODEL / 32), 256, 0, stream>>>(W_out, WoutT, DMODEL, DMODEL);

    gemm_bf16_mfma<0><<<dim3(3 * DMODEL / 128, M / 128), 256, 0, stream>>>(
        xb, WqkvT, b_qkv, qkvb, M, 3 * DMODEL, DMODEL);

    prep_vt<<<dim3(BATCH * NHEAD * (SEQ / 64)), 256, 0, stream>>>(qkvb, Vt);

    attn_mfma<<<dim3(BATCH * NHEAD * (SEQ / 128)), 256, 0, stream>>>(qkvb, Vt, attnb);

    gemm_bf16_mfma<1><<<dim3(DMODEL / 128, M / 128), 256, 0, stream>>>(
        attnb, WoutT, b_out, out, M, DMODEL, DMODEL);
}

// Round 3
// 308.326 us; speedup vs baseline: 18.3110x; 1.0970x over previous
//
#include <hip/hip_runtime.h>
#include <hip/hip_bf16.h>

#define SEQ 2048
#define BATCH 4
#define DMODEL 1024
#define NHEAD 16

// 0.125 (Dh^-0.5) * log2(e): folded into Q at the QKV-GEMM epilogue so the
// softmax can use exp2f directly.
#define QK_SCALE_LOG2E 0.1803368801111137f

typedef __attribute__((ext_vector_type(8))) __bf16 bf16x8;
typedef __attribute__((ext_vector_type(4))) __bf16 bf16x4;
typedef __attribute__((ext_vector_type(4))) float f32x4;

// async global->LDS, 16B per lane. LDS dest must be wave-uniform base; HW adds lane*16.
__device__ __forceinline__ void gload_lds16(const void* g, void* l) {
    __builtin_amdgcn_global_load_lds(
        (const __attribute__((address_space(1))) void*)g,
        (__attribute__((address_space(3))) void*)l, 16, 0, 0);
}

// ---------------- cast f32 -> bf16 (vectorized) ----------------
__global__ __launch_bounds__(256) void cast_f32_to_bf16(
    const float* __restrict__ in, __bf16* __restrict__ out, int n4)
{
    int i = blockIdx.x * 256 + threadIdx.x;
    if (i >= n4) return;
    float4 v = reinterpret_cast<const float4*>(in)[i];
    bf16x4 o = { (__bf16)v.x, (__bf16)v.y, (__bf16)v.z, (__bf16)v.w };
    reinterpret_cast<bf16x4*>(out)[i] = o;
}

// ---------------- W [K][N] f32 -> WT [N][K] bf16 ----------------
__global__ __launch_bounds__(256) void trans_w(
    const float* __restrict__ W, __bf16* __restrict__ WT, int K, int N)
{
    __shared__ float t[32][33];
    const int tid = threadIdx.x;
    const int n0 = blockIdx.x * 32, k0 = blockIdx.y * 32;
    const int tx = tid & 31, ty = tid >> 5;     // ty 0..7
    #pragma unroll
    for (int j = 0; j < 4; ++j)
        t[ty + 8*j][tx] = W[(size_t)(k0 + ty + 8*j) * N + n0 + tx];
    __syncthreads();
    #pragma unroll
    for (int j = 0; j < 4; ++j)
        WT[(size_t)(n0 + ty + 8*j) * K + k0 + tx] = (__bf16)t[tx][ty + 8*j];
}

// ---------------- V slice of qkv -> Vt [B*H][64][SEQ] ----------------
__global__ __launch_bounds__(256) void prep_vt(
    const __bf16* __restrict__ qkv, __bf16* __restrict__ Vt)
{
    __shared__ __bf16 t[64][72];
    const int tid = threadIdx.x;
    const int sc = blockIdx.x & 31, bh = blockIdx.x >> 5;
    const int b = bh >> 4, h = bh & 15;
    const size_t base = ((size_t)b * SEQ + sc * 64) * 3072 + 2 * DMODEL + h * 64;
    #pragma unroll
    for (int i = 0; i < 2; ++i) {
        int s = i * 32 + (tid >> 3), d0 = (tid & 7) * 8;
        bf16x8 v = *(const bf16x8*)&qkv[base + (size_t)s * 3072 + d0];
        #pragma unroll
        for (int j = 0; j < 8; ++j) t[s][d0 + j] = v[j];
    }
    __syncthreads();
    #pragma unroll
    for (int i = 0; i < 2; ++i) {
        int d = i * 32 + (tid >> 3), s0 = (tid & 7) * 8;
        bf16x8 v;
        #pragma unroll
        for (int j = 0; j < 8; ++j) v[j] = t[s0 + j][d];
        *(bf16x8*)&Vt[((size_t)bh * 64 + d) * SEQ + sc * 64 + s0] = v;
    }
}

// ---------------- m97-style bf16 MFMA GEMM: C = A[M,K] @ BT[N,K]^T + bias ----------------
// 128x128 tile, BK=32, 256 threads (4 waves 2x2), 16x16x32 MFMA, global_load_lds staging.
// QSCALE: multiply columns [0, DMODEL) by QK_SCALE_LOG2E (folds softmax scale into Q).
template<int F32OUT, int QSCALE>
__global__ __launch_bounds__(256) void gemm_bf16_mfma(
    const __bf16* __restrict__ A, const __bf16* __restrict__ BT,
    const float* __restrict__ bias, void* __restrict__ Cout,
    int M, int N, int K)
{
    __shared__ __attribute__((aligned(128))) char As[8192];   // [128][32] bf16
    __shared__ __attribute__((aligned(128))) char Bs[8192];   // [128][32] bf16

    const int tid = threadIdx.x, wv = tid >> 6, ln = tid & 63;
    const int rowBase = blockIdx.y * 128;
    const int colBase = blockIdx.x * 128;
    const int mq = (wv >> 1) * 64, nq = (wv & 1) * 64;
    const int lg = ln >> 4, lc = ln & 15;
    const int srow = ln >> 2;            // staging: row within 16-row chunk
    const int skoff = (ln & 3) * 8;      // staging: k elem offset

    f32x4 acc[4][4] = {};

    for (int k0 = 0; k0 < K; k0 += 32) {
        __syncthreads();
        #pragma unroll
        for (int i = 0; i < 2; ++i) {
            int ch = wv * 2 + i;         // 0..7, wave-uniform
            gload_lds16(A  + (size_t)(rowBase + ch*16 + srow) * K + k0 + skoff, As + ch*1024);
            gload_lds16(BT + (size_t)(colBase + ch*16 + srow) * K + k0 + skoff, Bs + ch*1024);
        }
        __syncthreads();

        bf16x8 af[4], bf[4];
        #pragma unroll
        for (int m = 0; m < 4; ++m)
            af[m] = *(const bf16x8*)(As + (mq + m*16 + lc) * 64 + lg * 16);
        #pragma unroll
        for (int n = 0; n < 4; ++n)
            bf[n] = *(const bf16x8*)(Bs + (nq + n*16 + lc) * 64 + lg * 16);
        #pragma unroll
        for (int m = 0; m < 4; ++m)
            #pragma unroll
            for (int n = 0; n < 4; ++n)
                acc[m][n] = __builtin_amdgcn_mfma_f32_16x16x32_bf16(af[m], bf[n], acc[m][n], 0, 0, 0);
    }

    #pragma unroll
    for (int m = 0; m < 4; ++m) {
        int row0 = rowBase + mq + m * 16 + lg * 4;
        #pragma unroll
        for (int n = 0; n < 4; ++n) {
            int col = colBase + nq + n * 16 + lc;
            float bv = bias[col];
            float sc = (QSCALE && col < DMODEL) ? QK_SCALE_LOG2E : 1.0f;
            #pragma unroll
            for (int r = 0; r < 4; ++r) {
                float v = (acc[m][n][r] + bv) * sc;
                if (F32OUT) ((float*)Cout)[(size_t)(row0 + r) * N + col] = v;
                else        ((__bf16*)Cout)[(size_t)(row0 + r) * N + col] = (__bf16)v;
            }
        }
    }
}

// ---------------- MFMA flash attention (swapped-operand, in-register softmax) ----------------
// block: 256 threads = 4 waves; each wave owns 32 q-rows; block = 128 q-rows of one (b,h).
// KV chunk = 64 keys, reg-staged (T14: issue loads for c+1 before compute of c).
// QK^T computed swapped: S^T[key][q] -> per-lane column softmax (2 shfls/m).
// PV computed swapped:   O^T[d][q]   -> alpha rescale needs no redistribution.
__global__ __launch_bounds__(256) void attn_mfma(
    const __bf16* __restrict__ qkv,   // [B][S][3072], Q pre-scaled by 0.125*log2e
    const __bf16* __restrict__ Vt,    // [B*H][64][SEQ]
    __bf16* __restrict__ attn_out)    // [B*S][DMODEL]
{
    __shared__ __attribute__((aligned(128))) char Ks[8192];      // [64 key][64 d] swizzled
    __shared__ __attribute__((aligned(128))) char Vs[8192];      // [64 d][64 key] swizzled
    __shared__ __attribute__((aligned(128))) char Ps[4][4096];   // per-wave [32 q][64 key] swizzled

    const int tid = threadIdx.x, wv = tid >> 6, ln = tid & 63;
    const int qt = blockIdx.x & 15;
    const int bh = blockIdx.x >> 4;
    const int b = bh >> 4, h = bh & 15;
    const int lg = ln >> 4, lc = ln & 15;

    const size_t qkvbase = (size_t)b * SEQ * 3072;

    // Q fragments in registers (already scaled by 0.125*log2e)
    bf16x8 qf[2][2];
    #pragma unroll
    for (int m = 0; m < 2; ++m) {
        int qrow = qt * 128 + wv * 32 + m * 16 + lc;
        #pragma unroll
        for (int t = 0; t < 2; ++t)
            qf[m][t] = *(const bf16x8*)&qkv[qkvbase + (size_t)qrow * 3072 + h * 64 + t * 32 + lg * 8];
    }

    f32x4 Oacc[4][2] = {};                 // [n = d-tile][m = q-tile], O^T layout
    float mrun[2] = {-1e30f, -1e30f};
    float lrun[2] = {0.f, 0.f};

    const int strow = ln >> 3;             // staging row within 8-row chunk
    const int sl8 = ln & 7;                // staging 8-elem slot

    // T14 reg-staging
    float4 kreg[2], vreg[2];
    const int srow0 = (wv * 2 + 0) * 8 + strow;
    const int srow1 = (wv * 2 + 1) * 8 + strow;

    {
        kreg[0] = *(const float4*)&qkv[qkvbase + (size_t)(0 * 64 + srow0) * 3072 + DMODEL + h * 64 + sl8 * 8];
        vreg[0] = *(const float4*)&Vt[((size_t)bh * 64 + srow0) * SEQ + 0 * 64 + sl8 * 8];
        kreg[1] = *(const float4*)&qkv[qkvbase + (size_t)(0 * 64 + srow1) * 3072 + DMODEL + h * 64 + sl8 * 8];
        vreg[1] = *(const float4*)&Vt[((size_t)bh * 64 + srow1) * SEQ + 0 * 64 + sl8 * 8];
    }

    char* PsW = Ps[wv];
    const int pxo = (lc & 7) << 4;
    const int sbyte0 = srow0 * 128 + ((sl8 * 16) ^ ((srow0 & 7) << 4));
    const int sbyte1 = srow1 * 128 + ((sl8 * 16) ^ ((srow1 & 7) << 4));

    for (int c = 0; c < SEQ / 64; ++c) {
        __syncthreads();                   // all waves done reading previous chunk
        *(float4*)(Ks + sbyte0) = kreg[0];
        *(float4*)(Vs + sbyte0) = vreg[0];
        *(float4*)(Ks + sbyte1) = kreg[1];
        *(float4*)(Vs + sbyte1) = vreg[1];
        if (c + 1 < SEQ / 64) {            // issue next-chunk loads; fly during compute
            kreg[0] = *(const float4*)&qkv[qkvbase + (size_t)((c+1) * 64 + srow0) * 3072 + DMODEL + h * 64 + sl8 * 8];
            vreg[0] = *(const float4*)&Vt[((size_t)bh * 64 + srow0) * SEQ + (c+1) * 64 + sl8 * 8];
            kreg[1] = *(const float4*)&qkv[qkvbase + (size_t)((c+1) * 64 + srow1) * 3072 + DMODEL + h * 64 + sl8 * 8];
            vreg[1] = *(const float4*)&Vt[((size_t)bh * 64 + srow1) * SEQ + (c+1) * 64 + sl8 * 8];
        }
        __syncthreads();                   // LDS chunk ready

        // ---- S^T = K Q^T (swapped) ----
        f32x4 Sacc[4][2] = {};
        #pragma unroll
        for (int n = 0; n < 4; ++n) {
            int row = n * 16 + lc;
            int xo = (row & 7) << 4;
            #pragma unroll
            for (int t = 0; t < 2; ++t) {
                bf16x8 kf = *(const bf16x8*)(Ks + row * 128 + ((t * 64 + lg * 16) ^ xo));
                #pragma unroll
                for (int m = 0; m < 2; ++m)
                    Sacc[n][m] = __builtin_amdgcn_mfma_f32_16x16x32_bf16(kf, qf[m][t], Sacc[n][m], 0, 0, 0);
            }
        }

        // ---- softmax: lane owns column q = m*16+lc, 16 key-values in-register ----
        #pragma unroll
        for (int m = 0; m < 2; ++m) {
            float mx = fmaxf(fmaxf(fmaxf(Sacc[0][m][0], Sacc[0][m][1]), fmaxf(Sacc[0][m][2], Sacc[0][m][3])),
                             fmaxf(fmaxf(Sacc[1][m][0], Sacc[1][m][1]), fmaxf(Sacc[1][m][2], Sacc[1][m][3])));
            mx = fmaxf(mx, fmaxf(fmaxf(fmaxf(Sacc[2][m][0], Sacc[2][m][1]), fmaxf(Sacc[2][m][2], Sacc[2][m][3])),
                                 fmaxf(fmaxf(Sacc[3][m][0], Sacc[3][m][1]), fmaxf(Sacc[3][m][2], Sacc[3][m][3]))));
            mx = fmaxf(mx, __shfl_xor(mx, 16));
            mx = fmaxf(mx, __shfl_xor(mx, 32));
            if (!__all(mx <= mrun[m] + 8.f)) {   // T13 defer-max
                float mnew = fmaxf(mrun[m], mx);
                float al = exp2f(mrun[m] - mnew);
                mrun[m] = mnew;
                lrun[m] *= al;
                #pragma unroll
                for (int n = 0; n < 4; ++n)
                    #pragma unroll
                    for (int r = 0; r < 4; ++r)
                        Oacc[n][m][r] *= al;
            }
            float pm = mrun[m];
            float psum = 0.f;
            #pragma unroll
            for (int n = 0; n < 4; ++n) {
                float p0 = exp2f(Sacc[n][m][0] - pm);
                float p1 = exp2f(Sacc[n][m][1] - pm);
                float p2 = exp2f(Sacc[n][m][2] - pm);
                float p3 = exp2f(Sacc[n][m][3] - pm);
                psum += (p0 + p1) + (p2 + p3);
                bf16x4 pk = { (__bf16)p0, (__bf16)p1, (__bf16)p2, (__bf16)p3 };
                // P[q = m*16+lc][keys n*16+lg*4 .. +3], swizzled row
                *(bf16x4*)(PsW + (m * 16 + lc) * 128 + (((n * 16 + lg * 4) * 2) ^ pxo)) = pk;
            }
            lrun[m] += psum;               // per-lane partial; cross-lg reduce deferred
        }

        // ---- O^T += V^T P^T (swapped; same-wave LDS, DS in-order, no barrier) ----
        #pragma unroll
        for (int t = 0; t < 2; ++t) {
            bf16x8 pf[2];
            #pragma unroll
            for (int m = 0; m < 2; ++m)
                pf[m] = *(const bf16x8*)(PsW + (m * 16 + lc) * 128 + ((t * 64 + lg * 16) ^ pxo));
            #pragma unroll
            for (int n = 0; n < 4; ++n) {
                int row = n * 16 + lc;
                bf16x8 vf = *(const bf16x8*)(Vs + row * 128 + ((t * 64 + lg * 16) ^ ((row & 7) << 4)));
                #pragma unroll
                for (int m = 0; m < 2; ++m)
                    Oacc[n][m] = __builtin_amdgcn_mfma_f32_16x16x32_bf16(vf, pf[m], Oacc[n][m], 0, 0, 0);
            }
        }
    }

    // ---- epilogue: finish l across lg groups, normalize, store ----
    #pragma unroll
    for (int m = 0; m < 2; ++m) {
        float l = lrun[m];
        l += __shfl_xor(l, 16);
        l += __shfl_xor(l, 32);
        float inv = 1.0f / l;
        int qrow = qt * 128 + wv * 32 + m * 16 + lc;
        #pragma unroll
        for (int n = 0; n < 4; ++n) {
            bf16x4 o = { (__bf16)(Oacc[n][m][0] * inv), (__bf16)(Oacc[n][m][1] * inv),
                         (__bf16)(Oacc[n][m][2] * inv), (__bf16)(Oacc[n][m][3] * inv) };
            *(bf16x4*)&attn_out[((size_t)b * SEQ + qrow) * DMODEL + h * 64 + n * 16 + lg * 4] = o;
        }
    }
}

extern "C" void kernel_launch(void* const* d_in, const int* in_sizes, int n_in,
                              void* d_out, int out_size, void* d_ws, size_t ws_size,
                              hipStream_t stream) {
    (void)in_sizes; (void)n_in; (void)out_size; (void)ws_size;
    const float* x     = (const float*)d_in[0];
    const float* W_qkv = (const float*)d_in[1];
    const float* b_qkv = (const float*)d_in[2];
    const float* W_out = (const float*)d_in[3];
    const float* b_out = (const float*)d_in[4];
    float* out = (float*)d_out;

    char* ws = (char*)d_ws;
    __bf16* xb    = (__bf16*)(ws);                          // 16 MB
    __bf16* WqkvT = (__bf16*)(ws + ((size_t)16 << 20));     // 6 MB
    __bf16* WoutT = (__bf16*)(ws + ((size_t)22 << 20));     // 2 MB
    __bf16* qkvb  = (__bf16*)(ws + ((size_t)24 << 20));     // 48 MB
    __bf16* Vt    = (__bf16*)(ws + ((size_t)72 << 20));     // 16 MB
    __bf16* attnb = (__bf16*)(ws + ((size_t)88 << 20));     // 16 MB

    const int M = BATCH * SEQ;  // 8192

    cast_f32_to_bf16<<<dim3(M * DMODEL / 4 / 256), 256, 0, stream>>>(x, xb, M * DMODEL / 4);
    trans_w<<<dim3(3 * DMODEL / 32, DMODEL / 32), 256, 0, stream>>>(W_qkv, WqkvT, DMODEL, 3 * DMODEL);
    trans_w<<<dim3(DMODEL / 32, DMODEL / 32), 256, 0, stream>>>(W_out, WoutT, DMODEL, DMODEL);

    gemm_bf16_mfma<0, 1><<<dim3(3 * DMODEL / 128, M / 128), 256, 0, stream>>>(
        xb, WqkvT, b_qkv, qkvb, M, 3 * DMODEL, DMODEL);

    prep_vt<<<dim3(BATCH * NHEAD * (SEQ / 64)), 256, 0, stream>>>(qkvb, Vt);

    attn_mfma<<<dim3(BATCH * NHEAD * (SEQ / 128)), 256, 0, stream>>>(qkvb, Vt, attnb);

    gemm_bf16_mfma<1, 0><<<dim3(DMODEL / 128, M / 128), 256, 0, stream>>>(
        attnb, WoutT, b_out, out, M, DMODEL, DMODEL);
}